// Round 6
// baseline (328.253 us; speedup 1.0000x reference)
//
#include <hip/hip_runtime.h>
#include <math.h>

#define NROWS 4096
#define DDIM  1024

typedef __attribute__((ext_vector_type(8))) short short8;
typedef __attribute__((ext_vector_type(4))) float f32x4;

// ---------- bf16 helpers (manual RNE) ----------
__device__ __forceinline__ ushort f2bf(float v) {
  union { float f; uint32_t u; } c; c.f = v;
  uint32_t u = c.u;
  uint32_t lsb = (u >> 16) & 1u;
  u += 0x7fffu + lsb;
  return (ushort)(u >> 16);
}
__device__ __forceinline__ float bf2f(ushort h) {
  union { uint32_t u; float f; } c; c.u = ((uint32_t)h) << 16;
  return c.f;
}

// ---------- s_sleep needs a literal immediate: constant-dispatch helper ----------
__device__ __forceinline__ void sleep_phase(int phase) {
  switch (phase & 15) {
    case 1:  __builtin_amdgcn_s_sleep(1);  break;
    case 2:  __builtin_amdgcn_s_sleep(2);  break;
    case 3:  __builtin_amdgcn_s_sleep(3);  break;
    case 4:  __builtin_amdgcn_s_sleep(4);  break;
    case 5:  __builtin_amdgcn_s_sleep(5);  break;
    case 6:  __builtin_amdgcn_s_sleep(6);  break;
    case 7:  __builtin_amdgcn_s_sleep(7);  break;
    case 8:  __builtin_amdgcn_s_sleep(8);  break;
    case 9:  __builtin_amdgcn_s_sleep(9);  break;
    case 10: __builtin_amdgcn_s_sleep(10); break;
    case 11: __builtin_amdgcn_s_sleep(11); break;
    case 12: __builtin_amdgcn_s_sleep(12); break;
    case 13: __builtin_amdgcn_s_sleep(13); break;
    case 14: __builtin_amdgcn_s_sleep(14); break;
    case 15: __builtin_amdgcn_s_sleep(15); break;
    default: break;
  }
}

// ---------- packed-fragment layouts ----------
// PLAIN: [R][C] bf16 as 16x32 tiles of 1KB (512 ushorts). tile T = (r>>4)*ldt+(c>>5);
//   intra ushort = ((c>>3)&3)*128 + (r&15)*8 + (c&7). Lane ln reads 16B at T*512+ln*8.
__device__ __forceinline__ size_t pidx(int r, int c, int ldt) {
  return ((size_t)((r >> 4) * ldt + (c >> 5))) * 512 +
         ((c >> 3) & 3) * 128 + (r & 15) * 8 + (c & 7);
}
// SPLIT-INTERLEAVED: hi fragment (512 ushorts) immediately followed by its lo
// fragment: tile T occupies 1024 ushorts; hi at T*1024+intra, lo at +512.
__device__ __forceinline__ size_t pidxs(int r, int c, int ldt) {
  return ((size_t)((r >> 4) * ldt + (c >> 5))) * 1024 +
         ((c >> 3) & 3) * 128 + (r & 15) * 8 + (c & 7);
}

// ---------- prep: split x + transpose/split 3 weights, packed outputs ----------
// X, Wq, Wk -> interleaved split planes; Wv -> plain (hi only).
// Raw inputs are read ONCE -> non-temporal loads (don't pollute L2/L3).
__global__ __launch_bounds__(256) void prep(const float* __restrict__ x,
                                            const float* __restrict__ wq,
                                            const float* __restrict__ wk,
                                            const float* __restrict__ wv,
                                            ushort* Xc,
                                            ushort* Wqc, ushort* Wkc, ushort* Wvh) {
  __shared__ float tl[32][33];
  const int b = blockIdx.x, t = threadIdx.x;
  if (b < 1024) {
    const f32x4* src = (const f32x4*)x;
#pragma unroll
    for (int r = 0; r < 4; ++r) {
      int i = b * 1024 + r * 256 + t;       // float4 index over [4096][256]
      int row = i >> 8;
      int c = (i & 255) << 2;               // 4-aligned column
      f32x4 v = __builtin_nontemporal_load(src + i);
      ushort4 h, l;
      h.x = f2bf(v.x); l.x = f2bf(v.x - bf2f(h.x));
      h.y = f2bf(v.y); l.y = f2bf(v.y - bf2f(h.y));
      h.z = f2bf(v.z); l.z = f2bf(v.z - bf2f(h.z));
      h.w = f2bf(v.w); l.w = f2bf(v.w - bf2f(h.w));
      size_t o = pidxs(row, c, DDIM / 32);  // (c&7)∈{0,4} -> 8B aligned
      *(ushort4*)(Xc + o) = h;
      *(ushort4*)(Xc + o + 512) = l;
    }
  } else {
    const int z = (b - 1024) >> 10;
    const int tile = (b - 1024) & 1023;
    const float* src = z == 0 ? wq : (z == 1 ? wk : wv);
    const int r0 = (tile >> 5) * 32;
    const int c0 = (tile & 31) * 32;
    const int tx = t & 31, ty = t >> 5;
    for (int i = ty; i < 32; i += 8)
      tl[i][tx] = __builtin_nontemporal_load(&src[(size_t)(r0 + i) * DDIM + c0 + tx]);
    __syncthreads();
    if (z == 2) {
      for (int i = ty; i < 32; i += 8) {
        float v = tl[tx][i];                // = W[r0+tx][c0+i]
        Wvh[pidx(c0 + i, r0 + tx, DDIM / 32)] = f2bf(v);
      }
    } else {
      ushort* d = z == 0 ? Wqc : Wkc;
      for (int i = ty; i < 32; i += 8) {
        float v = tl[tx][i];                // = W[r0+tx][c0+i]
        ushort h = f2bf(v);
        size_t o = pidxs(c0 + i, r0 + tx, DDIM / 32);  // W^T packed interleaved
        d[o] = h;
        d[o + 512] = f2bf(v - bf2f(h));
      }
    }
  }
}

// ---------- LDS-free, barrier-free direct packed-fragment GEMM core ----------
// Software-pipelined (distance-1 register double-buffer, static indices).
// MI = A-fragments/wave (wave tile MI*16 x 64). SA/SB = per-k-step ushort
// stride of A/B buffers (512 plain, 1024 split-interleaved). When SPLIT,
// lo plane sits at +512 ushorts (compiler folds as +1024B immediate).
template <int MI, bool SPLIT, int KT, int SA, int SB>
__device__ __forceinline__ void direct_gemm(const ushort* __restrict__ A,
                                            const ushort* __restrict__ B,
                                            int m0, int n0, f32x4 (*acc)[4]) {
  const int t = threadIdx.x;
  const int wv = t >> 6, ln = t & 63;
  const int arb = (wv >> 1) * (MI * 16), crb = (wv & 1) * 64;
  const int ra = (m0 + arb) >> 4;           // A tile-row base (frags ra..ra+MI-1)
  const int rb = (n0 + crb) >> 4;

  uint oA[MI], oB[4];
#pragma unroll
  for (int i = 0; i < MI; ++i) oA[i] = (uint)(ra + i) * (uint)(KT * SA) + (uint)ln * 8u;
#pragma unroll
  for (int j = 0; j < 4; ++j) oB[j] = (uint)(rb + j) * (uint)(KT * SB) + (uint)ln * 8u;

  short8 ah0[MI], al0[MI], bh0[4], bl0[4];
  short8 ah1[MI], al1[MI], bh1[4], bl1[4];

#define DG_LOAD(sidx, AH, AL, BH, BL)                                        \
  {                                                                          \
    uint sa_ = (uint)(sidx) * (uint)SA;                                      \
    uint sb_ = (uint)(sidx) * (uint)SB;                                      \
    _Pragma("unroll") for (int i_ = 0; i_ < MI; ++i_) {                      \
      const ushort* pa_ = A + oA[i_] + sa_;                                  \
      AH[i_] = *(const short8*)pa_;                                          \
      if constexpr (SPLIT) AL[i_] = *(const short8*)(pa_ + 512);             \
    }                                                                        \
    _Pragma("unroll") for (int j_ = 0; j_ < 4; ++j_) {                       \
      const ushort* pb_ = B + oB[j_] + sb_;                                  \
      BH[j_] = *(const short8*)pb_;                                          \
      if constexpr (SPLIT) BL[j_] = *(const short8*)(pb_ + 512);             \
    }                                                                        \
  }

#define DG_MFMA(AH, AL, BH, BL)                                              \
  {                                                                          \
    __builtin_amdgcn_s_setprio(1);                                           \
    _Pragma("unroll") for (int j_ = 0; j_ < 4; ++j_) {                       \
      _Pragma("unroll") for (int i_ = 0; i_ < MI; ++i_) {                    \
        acc[i_][j_] = __builtin_amdgcn_mfma_f32_16x16x32_bf16(               \
            AH[i_], BH[j_], acc[i_][j_], 0, 0, 0);                           \
        if constexpr (SPLIT) {                                               \
          acc[i_][j_] = __builtin_amdgcn_mfma_f32_16x16x32_bf16(             \
              AH[i_], BL[j_], acc[i_][j_], 0, 0, 0);                         \
          acc[i_][j_] = __builtin_amdgcn_mfma_f32_16x16x32_bf16(             \
              AL[i_], BH[j_], acc[i_][j_], 0, 0, 0);                         \
        }                                                                    \
      }                                                                      \
    }                                                                        \
    __builtin_amdgcn_s_setprio(0);                                           \
  }

  DG_LOAD(0, ah0, al0, bh0, bl0);
#pragma unroll 1
  for (int s = 0; s < KT - 2; s += 2) {
    DG_LOAD(s + 1, ah1, al1, bh1, bl1);
    DG_MFMA(ah0, al0, bh0, bl0);
    DG_LOAD(s + 2, ah0, al0, bh0, bl0);
    DG_MFMA(ah1, al1, bh1, bl1);
  }
  DG_LOAD(KT - 1, ah1, al1, bh1, bl1);
  DG_MFMA(ah0, al0, bh0, bl0);
  DG_MFMA(ah1, al1, bh1, bl1);

#undef DG_LOAD
#undef DG_MFMA
}

// ---------- fused QKV: direct-packed, no LDS, no barriers; XCD-chunked swizzle ----------
__global__ __launch_bounds__(256) void gemm_qkv(const ushort* __restrict__ Xc,
                                                const ushort* __restrict__ Wqc,
                                                const ushort* __restrict__ Wkc,
                                                const ushort* __restrict__ Wvh,
                                                ushort* Qc, ushort* Kc, ushort* Vt) {
  // grid (24,32) = 768 blocks; dispatch id -> XCD = id%8. Give each XCD 96
  // contiguous wgs (4 full by-rows): X panels shared, W set streams.
  const int id = blockIdx.y * 24 + blockIdx.x;
  const int wg = (id & 7) * 96 + (id >> 3);
  const int bx = wg % 24, by = wg / 24;
  const int which = bx % 3;
  const int g = bx / 3;                      // 0..7 (d_out slice)
  const int t = threadIdx.x;
  const int wv = t >> 6, ln = t & 63;
  const int quad = ln >> 4, l16 = ln & 15;

  // phase-stagger co-resident blocks/waves (co-CU blocks have consecutive id>>3)
  sleep_phase((((id >> 3) & 3) << 2) | wv);

  f32x4 acc[4][4];
#pragma unroll
  for (int i = 0; i < 4; ++i)
#pragma unroll
    for (int j = 0; j < 4; ++j) acc[i][j] = (f32x4){0.f, 0.f, 0.f, 0.f};

  if (which == 2) {
    // Vt[d][kv] = sum_k WvT[d][k] * X[kv][k]  (= V[kv][d]) -> plain packed
    const int m0 = g * 128;                  // d over 1024
    const int n0 = by * 128;                 // kv over 4096
    direct_gemm<4, false, DDIM / 32, 512, 1024>(Wvh, Xc, m0, n0, acc);
#pragma unroll
    for (int i = 0; i < 4; ++i)
#pragma unroll
      for (int j = 0; j < 4; ++j) {
        int kv = n0 + (wv & 1) * 64 + j * 16 + l16;
        int d = m0 + (wv >> 1) * 64 + i * 16 + quad * 4;
#pragma unroll
        for (int r2 = 0; r2 < 4; ++r2)
          Vt[pidx(d + r2, kv, NROWS / 32)] = f2bf(acc[i][j][r2]);
      }
  } else {
    const int n0 = g * 128;                  // d over 1024
    const int m0 = by * 128;                 // rows over 4096
    const ushort* Bc = which ? Wkc : Wqc;
    direct_gemm<4, true, DDIM / 32, 1024, 1024>(Xc, Bc, m0, n0, acc);
    const float scale = which ? 1.0f : 0.03125f;  // fold 1/sqrt(1024) into Q
    ushort* D = which ? Kc : Qc;
#pragma unroll
    for (int i = 0; i < 4; ++i)
#pragma unroll
      for (int j = 0; j < 4; ++j) {
        int col = n0 + (wv & 1) * 64 + j * 16 + l16;
        int rw = m0 + (wv >> 1) * 64 + i * 16 + quad * 4;
#pragma unroll
        for (int r2 = 0; r2 < 4; ++r2) {
          float v = acc[i][j][r2] * scale;
          ushort h = f2bf(v);
          size_t o = pidxs(rw + r2, col, DDIM / 32);
          D[o] = h;
          D[o + 512] = f2bf(v - bf2f(h));
        }
      }
  }
}

// ---------- S = Q*K^T (split), LDS-free, barrier-free; XCD 2D-chunked swizzle ----------
__global__ __launch_bounds__(256) void gemm_s(const ushort* __restrict__ Qc,
                                              const ushort* __restrict__ Kc,
                                              float* __restrict__ S) {
  // grid 32x32 = 1024; XCD = bid%8. Each XCD: 8-row x 16-col region,
  // row-fastest order -> 8 Q-panels stay L2-resident, K streams.
  const int bid = blockIdx.y * 32 + blockIdx.x;
  const int xcd = bid & 7, local = bid >> 3;
  const int band = xcd >> 1, half = xcd & 1;
  const int row_l = local & 7, col_l = local >> 3;
  const int m0 = (band * 8 + row_l) * 128;
  const int n0 = (half * 16 + col_l) * 128;
  const int t = threadIdx.x;
  const int wv = t >> 6, ln = t & 63;
  const int quad = ln >> 4, l16 = ln & 15;

  // phase-stagger co-resident blocks/waves (co-CU blocks have consecutive local)
  sleep_phase(((local & 3) << 2) | wv);

  f32x4 acc[4][4];
#pragma unroll
  for (int i = 0; i < 4; ++i)
#pragma unroll
    for (int j = 0; j < 4; ++j) acc[i][j] = (f32x4){0.f, 0.f, 0.f, 0.f};

  direct_gemm<4, true, DDIM / 32, 1024, 1024>(Qc, Kc, m0, n0, acc);

  // S is written once and read once (softmax): non-temporal -> don't evict Q/K
#pragma unroll
  for (int i = 0; i < 4; ++i)
#pragma unroll
    for (int j = 0; j < 4; ++j) {
      int col = n0 + (wv & 1) * 64 + j * 16 + l16;
      int rw = m0 + (wv >> 1) * 64 + i * 16 + quad * 4;
#pragma unroll
      for (int r2 = 0; r2 < 4; ++r2)
        __builtin_nontemporal_store(acc[i][j][r2],
                                    &S[(size_t)(rw + r2) * NROWS + col]);
    }
}

// ---------- softmax: row of S (fp32) -> PACKED bf16 P (plain layout) ----------
__global__ __launch_bounds__(256) void softmax_pack(const float* __restrict__ S,
                                                    ushort* __restrict__ P) {
  const int row = blockIdx.x, t = threadIdx.x;
  const float* Sr = S + (size_t)row * NROWS;
  const f32x4* S4 = (const f32x4*)Sr;
  f32x4 v[4];
  float mx = -3.4e38f;
#pragma unroll
  for (int c = 0; c < 4; ++c) {
    v[c] = __builtin_nontemporal_load(S4 + c * 256 + t);
    mx = fmaxf(mx, fmaxf(fmaxf(v[c].x, v[c].y), fmaxf(v[c].z, v[c].w)));
  }
  __shared__ float red[4];
  for (int o = 32; o >= 1; o >>= 1) mx = fmaxf(mx, __shfl_xor(mx, o));
  int wv = t >> 6, ln = t & 63;
  if (ln == 0) red[wv] = mx;
  __syncthreads();
  mx = fmaxf(fmaxf(red[0], red[1]), fmaxf(red[2], red[3]));
  float s = 0.f;
#pragma unroll
  for (int c = 0; c < 4; ++c) {
    v[c].x = __expf(v[c].x - mx);
    v[c].y = __expf(v[c].y - mx);
    v[c].z = __expf(v[c].z - mx);
    v[c].w = __expf(v[c].w - mx);
    s += v[c].x + v[c].y + v[c].z + v[c].w;
  }
  for (int o = 32; o >= 1; o >>= 1) s += __shfl_xor(s, o);
  __syncthreads();
  if (ln == 0) red[wv] = s;
  __syncthreads();
  s = red[0] + red[1] + red[2] + red[3];
  float inv = 1.f / s;
#pragma unroll
  for (int c = 0; c < 4; ++c) {
    ushort4 h;
    h.x = f2bf(v[c].x * inv);
    h.y = f2bf(v[c].y * inv);
    h.z = f2bf(v[c].z * inv);
    h.w = f2bf(v[c].w * inv);
    int c0 = 1024 * c + 4 * t;            // 4 consecutive cols, 8B-aligned in packed space
    *(ushort4*)(P + pidx(row, c0, NROWS / 32)) = h;
  }
}

// ---------- Out = P*V, LDS-free, barrier-free; BM=128 ----------
// grid (8,32): dispatch id%8 == bx -> each XCD naturally owns one Vt stripe.
__global__ __launch_bounds__(256) void gemm_pv(const ushort* __restrict__ P,
                                               const ushort* __restrict__ Vt,
                                               float* __restrict__ Out) {
  const int n0 = blockIdx.x * 128, m0 = blockIdx.y * 128;
  const int t = threadIdx.x;
  const int wv = t >> 6, ln = t & 63;
  const int quad = ln >> 4, l16 = ln & 15;

  // phase-stagger (co-CU blocks share bx, consecutive by)
  sleep_phase(((blockIdx.y & 3) << 2) | wv);

  f32x4 acc[4][4];
#pragma unroll
  for (int i = 0; i < 4; ++i)
#pragma unroll
    for (int j = 0; j < 4; ++j) acc[i][j] = (f32x4){0.f, 0.f, 0.f, 0.f};

  direct_gemm<4, false, NROWS / 32, 512, 512>(P, Vt, m0, n0, acc);

#pragma unroll
  for (int i = 0; i < 4; ++i)
#pragma unroll
    for (int j = 0; j < 4; ++j) {
      int col = n0 + (wv & 1) * 64 + j * 16 + l16;
      int rw = m0 + (wv >> 1) * 64 + i * 16 + quad * 4;
#pragma unroll
      for (int r2 = 0; r2 < 4; ++r2)
        __builtin_nontemporal_store(acc[i][j][r2],
                                    &Out[(size_t)(rw + r2) * DDIM + col]);
    }
}

extern "C" void kernel_launch(void* const* d_in, const int* in_sizes, int n_in,
                              void* d_out, int out_size, void* d_ws, size_t ws_size,
                              hipStream_t stream) {
  const float* x  = (const float*)d_in[0];
  const float* wq = (const float*)d_in[1];
  const float* wk = (const float*)d_in[2];
  const float* wv = (const float*)d_in[3];
  char* ws = (char*)d_ws;
  const size_t MB = 1u << 20;

  // Workspace map (peak 104 MiB):
  ushort* Vt  = (ushort*)(ws + 0);        // 0-8    plain packed, alive through pv
  ushort* Qc  = (ushort*)(ws + 8 * MB);   // 8-24   interleaved split Q (dead after gemm_s)
  ushort* Kc  = (ushort*)(ws + 24 * MB);  // 24-40  interleaved split K (dead after gemm_s)
  ushort* Pp  = (ushort*)(ws + 8 * MB);   // 8-40   plain packed P (aliases dead Q/K)
  ushort* Xc  = (ushort*)(ws + 40 * MB);  // 40-56  interleaved split X (dead after qkv)
  ushort* Wqc = (ushort*)(ws + 56 * MB);  // 56-60  interleaved split W^T (dead after qkv)
  ushort* Wkc = (ushort*)(ws + 60 * MB);  // 60-64
  ushort* Wvh = (ushort*)(ws + 64 * MB);  // 64-66  plain W_v^T
  float*  S   = (float*)(ws + 40 * MB);   // 40-104 (overwrites dead X/W)
  float*  Out = (float*)d_out;

  prep<<<4096, 256, 0, stream>>>(x, wq, wk, wv, Xc, Wqc, Wkc, Wvh);
  gemm_qkv<<<dim3(24, 32), 256, 0, stream>>>(Xc, Wqc, Wkc, Wvh, Qc, Kc, Vt);
  gemm_s<<<dim3(32, 32), 256, 0, stream>>>(Qc, Kc, S);
  softmax_pack<<<NROWS, 256, 0, stream>>>(S, Pp);
  gemm_pv<<<dim3(8, 32), 256, 0, stream>>>(Pp, Vt, Out);
}

// Round 8
// 315.430 us; speedup vs baseline: 1.0407x; 1.0407x over previous
//
#include <hip/hip_runtime.h>
#include <math.h>

#define NROWS 4096
#define DDIM  1024

typedef __attribute__((ext_vector_type(8))) short short8;
typedef __attribute__((ext_vector_type(4))) float f32x4;

// ---------- bf16 helpers (manual RNE) ----------
__device__ __forceinline__ ushort f2bf(float v) {
  union { float f; uint32_t u; } c; c.f = v;
  uint32_t u = c.u;
  uint32_t lsb = (u >> 16) & 1u;
  u += 0x7fffu + lsb;
  return (ushort)(u >> 16);
}
__device__ __forceinline__ float bf2f(ushort h) {
  union { uint32_t u; float f; } c; c.u = ((uint32_t)h) << 16;
  return c.f;
}

// ---------- async global->LDS, 16B per lane ----------
__device__ __forceinline__ void gll16(const void* g, void* l) {
  __builtin_amdgcn_global_load_lds((const __attribute__((address_space(1))) void*)g,
                                   (__attribute__((address_space(3))) void*)l, 16, 0, 0);
}

// ---------- packed-fragment layouts ----------
// PLAIN: [R][C] bf16 as 16x32 tiles of 1KB (512 ushorts). tile T = (r>>4)*ldt+(c>>5);
//   intra ushort = ((c>>3)&3)*128 + (r&15)*8 + (c&7). Lane ln reads 16B at T*512+ln*8.
__device__ __forceinline__ size_t pidx(int r, int c, int ldt) {
  return ((size_t)((r >> 4) * ldt + (c >> 5))) * 512 +
         ((c >> 3) & 3) * 128 + (r & 15) * 8 + (c & 7);
}
// SPLIT-INTERLEAVED: hi fragment (512 ushorts) immediately followed by its lo
// fragment: tile T occupies 1024 ushorts; hi at T*1024+intra, lo at +512.
__device__ __forceinline__ size_t pidxs(int r, int c, int ldt) {
  return ((size_t)((r >> 4) * ldt + (c >> 5))) * 1024 +
         ((c >> 3) & 3) * 128 + (r & 15) * 8 + (c & 7);
}

// ---------- prep: split x + transpose/split 3 weights, packed outputs ----------
__global__ __launch_bounds__(256) void prep(const float* __restrict__ x,
                                            const float* __restrict__ wq,
                                            const float* __restrict__ wk,
                                            const float* __restrict__ wv,
                                            ushort* Xc,
                                            ushort* Wqc, ushort* Wkc, ushort* Wvh) {
  __shared__ float tl[32][33];
  const int b = blockIdx.x, t = threadIdx.x;
  if (b < 1024) {
    const f32x4* src = (const f32x4*)x;
#pragma unroll
    for (int r = 0; r < 4; ++r) {
      int i = b * 1024 + r * 256 + t;       // float4 index over [4096][256]
      int row = i >> 8;
      int c = (i & 255) << 2;               // 4-aligned column
      f32x4 v = __builtin_nontemporal_load(src + i);
      ushort4 h, l;
      h.x = f2bf(v.x); l.x = f2bf(v.x - bf2f(h.x));
      h.y = f2bf(v.y); l.y = f2bf(v.y - bf2f(h.y));
      h.z = f2bf(v.z); l.z = f2bf(v.z - bf2f(h.z));
      h.w = f2bf(v.w); l.w = f2bf(v.w - bf2f(h.w));
      size_t o = pidxs(row, c, DDIM / 32);  // (c&7)∈{0,4} -> 8B aligned
      *(ushort4*)(Xc + o) = h;
      *(ushort4*)(Xc + o + 512) = l;
    }
  } else {
    const int z = (b - 1024) >> 10;
    const int tile = (b - 1024) & 1023;
    const float* src = z == 0 ? wq : (z == 1 ? wk : wv);
    const int r0 = (tile >> 5) * 32;
    const int c0 = (tile & 31) * 32;
    const int tx = t & 31, ty = t >> 5;
    for (int i = ty; i < 32; i += 8)
      tl[i][tx] = __builtin_nontemporal_load(&src[(size_t)(r0 + i) * DDIM + c0 + tx]);
    __syncthreads();
    if (z == 2) {
      for (int i = ty; i < 32; i += 8) {
        float v = tl[tx][i];                // = W[r0+tx][c0+i]
        Wvh[pidx(c0 + i, r0 + tx, DDIM / 32)] = f2bf(v);
      }
    } else {
      ushort* d = z == 0 ? Wqc : Wkc;
      for (int i = ty; i < 32; i += 8) {
        float v = tl[tx][i];                // = W[r0+tx][c0+i]
        ushort h = f2bf(v);
        size_t o = pidxs(c0 + i, r0 + tx, DDIM / 32);  // W^T packed interleaved
        d[o] = h;
        d[o + 512] = f2bf(v - bf2f(h));
      }
    }
  }
}

// ---------- LDS-free, barrier-free direct packed-fragment GEMM core ----------
// (kept for gemm_qkv / gemm_pv)
template <int MI, bool SPLIT, int KT, int SA, int SB>
__device__ __forceinline__ void direct_gemm(const ushort* __restrict__ A,
                                            const ushort* __restrict__ B,
                                            int m0, int n0, f32x4 (*acc)[4]) {
  const int t = threadIdx.x;
  const int wv = t >> 6, ln = t & 63;
  const int arb = (wv >> 1) * (MI * 16), crb = (wv & 1) * 64;
  const int ra = (m0 + arb) >> 4;
  const int rb = (n0 + crb) >> 4;

  uint oA[MI], oB[4];
#pragma unroll
  for (int i = 0; i < MI; ++i) oA[i] = (uint)(ra + i) * (uint)(KT * SA) + (uint)ln * 8u;
#pragma unroll
  for (int j = 0; j < 4; ++j) oB[j] = (uint)(rb + j) * (uint)(KT * SB) + (uint)ln * 8u;

  short8 ah0[MI], al0[MI], bh0[4], bl0[4];
  short8 ah1[MI], al1[MI], bh1[4], bl1[4];

#define DG_LOAD(sidx, AH, AL, BH, BL)                                        \
  {                                                                          \
    uint sa_ = (uint)(sidx) * (uint)SA;                                      \
    uint sb_ = (uint)(sidx) * (uint)SB;                                      \
    _Pragma("unroll") for (int i_ = 0; i_ < MI; ++i_) {                      \
      const ushort* pa_ = A + oA[i_] + sa_;                                  \
      AH[i_] = *(const short8*)pa_;                                          \
      if constexpr (SPLIT) AL[i_] = *(const short8*)(pa_ + 512);             \
    }                                                                        \
    _Pragma("unroll") for (int j_ = 0; j_ < 4; ++j_) {                       \
      const ushort* pb_ = B + oB[j_] + sb_;                                  \
      BH[j_] = *(const short8*)pb_;                                          \
      if constexpr (SPLIT) BL[j_] = *(const short8*)(pb_ + 512);             \
    }                                                                        \
  }

#define DG_MFMA(AH, AL, BH, BL)                                              \
  {                                                                          \
    __builtin_amdgcn_s_setprio(1);                                           \
    _Pragma("unroll") for (int j_ = 0; j_ < 4; ++j_) {                       \
      _Pragma("unroll") for (int i_ = 0; i_ < MI; ++i_) {                    \
        acc[i_][j_] = __builtin_amdgcn_mfma_f32_16x16x32_bf16(               \
            AH[i_], BH[j_], acc[i_][j_], 0, 0, 0);                           \
        if constexpr (SPLIT) {                                               \
          acc[i_][j_] = __builtin_amdgcn_mfma_f32_16x16x32_bf16(             \
              AH[i_], BL[j_], acc[i_][j_], 0, 0, 0);                         \
          acc[i_][j_] = __builtin_amdgcn_mfma_f32_16x16x32_bf16(             \
              AL[i_], BH[j_], acc[i_][j_], 0, 0, 0);                         \
        }                                                                    \
      }                                                                      \
    }                                                                        \
    __builtin_amdgcn_s_setprio(0);                                           \
  }

  DG_LOAD(0, ah0, al0, bh0, bl0);
#pragma unroll 1
  for (int s = 0; s < KT - 2; s += 2) {
    DG_LOAD(s + 1, ah1, al1, bh1, bl1);
    DG_MFMA(ah0, al0, bh0, bl0);
    DG_LOAD(s + 2, ah0, al0, bh0, bl0);
    DG_MFMA(ah1, al1, bh1, bl1);
  }
  DG_LOAD(KT - 1, ah1, al1, bh1, bl1);
  DG_MFMA(ah0, al0, bh0, bl0);
  DG_MFMA(ah1, al1, bh1, bl1);

#undef DG_LOAD
#undef DG_MFMA
}

// ---------- fused QKV: direct-packed, no LDS, no barriers; XCD-chunked swizzle ----------
__global__ __launch_bounds__(256) void gemm_qkv(const ushort* __restrict__ Xc,
                                                const ushort* __restrict__ Wqc,
                                                const ushort* __restrict__ Wkc,
                                                const ushort* __restrict__ Wvh,
                                                ushort* Qc, ushort* Kc, ushort* Vt) {
  const int id = blockIdx.y * 24 + blockIdx.x;
  const int wg = (id & 7) * 96 + (id >> 3);
  const int bx = wg % 24, by = wg / 24;
  const int which = bx % 3;
  const int g = bx / 3;                      // 0..7 (d_out slice)
  const int t = threadIdx.x;
  const int wv = t >> 6, ln = t & 63;
  const int quad = ln >> 4, l16 = ln & 15;

  f32x4 acc[4][4];
#pragma unroll
  for (int i = 0; i < 4; ++i)
#pragma unroll
    for (int j = 0; j < 4; ++j) acc[i][j] = (f32x4){0.f, 0.f, 0.f, 0.f};

  if (which == 2) {
    const int m0 = g * 128;                  // d over 1024
    const int n0 = by * 128;                 // kv over 4096
    direct_gemm<4, false, DDIM / 32, 512, 1024>(Wvh, Xc, m0, n0, acc);
#pragma unroll
    for (int i = 0; i < 4; ++i)
#pragma unroll
      for (int j = 0; j < 4; ++j) {
        int kv = n0 + (wv & 1) * 64 + j * 16 + l16;
        int d = m0 + (wv >> 1) * 64 + i * 16 + quad * 4;
#pragma unroll
        for (int r2 = 0; r2 < 4; ++r2)
          Vt[pidx(d + r2, kv, NROWS / 32)] = f2bf(acc[i][j][r2]);
      }
  } else {
    const int n0 = g * 128;                  // d over 1024
    const int m0 = by * 128;                 // rows over 4096
    const ushort* Bc = which ? Wkc : Wqc;
    direct_gemm<4, true, DDIM / 32, 1024, 1024>(Xc, Bc, m0, n0, acc);
    const float scale = which ? 1.0f : 0.03125f;  // fold 1/sqrt(1024) into Q
    ushort* D = which ? Kc : Qc;
#pragma unroll
    for (int i = 0; i < 4; ++i)
#pragma unroll
      for (int j = 0; j < 4; ++j) {
        int col = n0 + (wv & 1) * 64 + j * 16 + l16;
        int rw = m0 + (wv >> 1) * 64 + i * 16 + quad * 4;
#pragma unroll
        for (int r2 = 0; r2 < 4; ++r2) {
          float v = acc[i][j][r2] * scale;
          ushort h = f2bf(v);
          size_t o = pidxs(rw + r2, col, DDIM / 32);
          D[o] = h;
          D[o + 512] = f2bf(v - bf2f(h));
        }
      }
  }
}

// ---------- S = Q*K^T (split): 256x256 tile, 8 waves, 4-phase LDS schedule ----------
// Double-buffered 128KB LDS; packed fragments -> linear gll16 staging and
// conflict-free contiguous ds_read_b128. Stage tile kt+1 during phases 0/1 of
// tile kt; per-wave vmcnt(0) BEFORE the phase-3 closing barrier makes every
// wave's staging visible to all waves' tile-kt+1 reads. Phase p consumes A
// frag-pairs (2p, 2p+1) at byte offsets (2p)*2048 / (2p+1)*2048.
__global__ __launch_bounds__(512) void gemm_s(const ushort* __restrict__ Qc,
                                              const ushort* __restrict__ Kc,
                                              float* __restrict__ S) {
  __shared__ char smem[2][65536];
  const int bid = blockIdx.y * 16 + blockIdx.x;
  const int xcd = bid & 7, local = bid >> 3;   // 256 blocks = 1/CU
  // XCD region: 4 tile-rows x 8 tile-cols (bijective)
  const int m0 = ((xcd >> 1) * 4 + (local & 3)) * 256;
  const int n0 = ((xcd & 1) * 8 + (local >> 2)) * 256;
  const int t = threadIdx.x;
  const int w = t >> 6, ln = t & 63;
  const int wr = w >> 2, wc = w & 3;           // 2(M) x 4(N) wave grid
  const int quad = ln >> 4, l16 = ln & 15;

  // ---- staging source: each wave stages 4 frag-pairs (8KB) per tile ----
  // frag-row stride = 32 tiles * 2048B = 65536B
  const char* srcBase = (w < 4)
      ? (const char*)Qc + (size_t)((m0 >> 4) + w * 4) * 65536
      : (const char*)Kc + (size_t)((n0 >> 4) + (w - 4) * 4) * 65536;
  srcBase += ln * 16;
  char* ldsBase = (char*)smem + w * 8192 + ln * 16;  // + buf*65536 + u*1024

  f32x4 acc[8][4];
#pragma unroll
  for (int i = 0; i < 8; ++i)
#pragma unroll
    for (int j = 0; j < 4; ++j) acc[i][j] = (f32x4){0.f, 0.f, 0.f, 0.f};

  // ---- prologue: stage tile 0 into buf 0 ----
#pragma unroll
  for (int u = 0; u < 8; ++u)
    gll16(srcBase + (u >> 1) * 65536 + (u & 1) * 1024, ldsBase + u * 1024);
  asm volatile("s_waitcnt vmcnt(0)" ::: "memory");
  __builtin_amdgcn_s_barrier();

  const char* aB = (char*)smem + (wr * 8) * 2048 + ln * 16;
  const char* bB = (char*)smem + 32768 + (wc * 4) * 2048 + ln * 16;

#define S_MFMA_PAIR(I, AH0, AL0, AH1, AL1)                                    \
  {                                                                           \
    __builtin_amdgcn_s_setprio(1);                                            \
    _Pragma("unroll") for (int j_ = 0; j_ < 4; ++j_) {                        \
      acc[I][j_] = __builtin_amdgcn_mfma_f32_16x16x32_bf16(AH0, bh[j_], acc[I][j_], 0, 0, 0);       \
      acc[I][j_] = __builtin_amdgcn_mfma_f32_16x16x32_bf16(AH0, bl[j_], acc[I][j_], 0, 0, 0);       \
      acc[I][j_] = __builtin_amdgcn_mfma_f32_16x16x32_bf16(AL0, bh[j_], acc[I][j_], 0, 0, 0);       \
      acc[I + 1][j_] = __builtin_amdgcn_mfma_f32_16x16x32_bf16(AH1, bh[j_], acc[I + 1][j_], 0, 0, 0); \
      acc[I + 1][j_] = __builtin_amdgcn_mfma_f32_16x16x32_bf16(AH1, bl[j_], acc[I + 1][j_], 0, 0, 0); \
      acc[I + 1][j_] = __builtin_amdgcn_mfma_f32_16x16x32_bf16(AL1, bh[j_], acc[I + 1][j_], 0, 0, 0); \
    }                                                                         \
    __builtin_amdgcn_s_setprio(0);                                            \
  }

#pragma unroll 1
  for (int kt = 0; kt < 32; ++kt) {
    const int cb = (kt & 1) << 16;             // current buffer byte offset
    const int nb = ((kt + 1) & 1) << 16;       // next buffer byte offset
    const char* srcK = srcBase + (size_t)(kt + 1) * 2048;

    short8 bh[4], bl[4], ah0, al0, ah1, al1;

    // ---- phase 0: read B(all) + A frags 0,1; stage half of tile kt+1 ----
#pragma unroll
    for (int j = 0; j < 4; ++j) {
      bh[j] = *(const short8*)(bB + cb + j * 2048);
      bl[j] = *(const short8*)(bB + cb + j * 2048 + 1024);
    }
    ah0 = *(const short8*)(aB + cb + 0 * 2048);
    al0 = *(const short8*)(aB + cb + 0 * 2048 + 1024);
    ah1 = *(const short8*)(aB + cb + 1 * 2048);
    al1 = *(const short8*)(aB + cb + 1 * 2048 + 1024);
    if (kt < 31) {
#pragma unroll
      for (int u = 0; u < 4; ++u)
        gll16(srcK + (u >> 1) * 65536 + (u & 1) * 1024, ldsBase + nb + u * 1024);
    }
    __builtin_amdgcn_s_barrier();
    S_MFMA_PAIR(0, ah0, al0, ah1, al1);
    __builtin_amdgcn_s_barrier();

    // ---- phase 1: read A frags 2,3; stage other half ----
    ah0 = *(const short8*)(aB + cb + 2 * 2048);
    al0 = *(const short8*)(aB + cb + 2 * 2048 + 1024);
    ah1 = *(const short8*)(aB + cb + 3 * 2048);
    al1 = *(const short8*)(aB + cb + 3 * 2048 + 1024);
    if (kt < 31) {
#pragma unroll
      for (int u = 4; u < 8; ++u)
        gll16(srcK + (u >> 1) * 65536 + (u & 1) * 1024, ldsBase + nb + u * 1024);
    }
    __builtin_amdgcn_s_barrier();
    S_MFMA_PAIR(2, ah0, al0, ah1, al1);
    __builtin_amdgcn_s_barrier();

    // ---- phase 2: read A frags 4,5 ----
    ah0 = *(const short8*)(aB + cb + 4 * 2048);
    al0 = *(const short8*)(aB + cb + 4 * 2048 + 1024);
    ah1 = *(const short8*)(aB + cb + 5 * 2048);
    al1 = *(const short8*)(aB + cb + 5 * 2048 + 1024);
    __builtin_amdgcn_s_barrier();
    S_MFMA_PAIR(4, ah0, al0, ah1, al1);
    __builtin_amdgcn_s_barrier();

    // ---- phase 3: read A frags 6,7; drain own staging BEFORE closing barrier ----
    ah0 = *(const short8*)(aB + cb + 6 * 2048);
    al0 = *(const short8*)(aB + cb + 6 * 2048 + 1024);
    ah1 = *(const short8*)(aB + cb + 7 * 2048);
    al1 = *(const short8*)(aB + cb + 7 * 2048 + 1024);
    __builtin_amdgcn_s_barrier();
    S_MFMA_PAIR(6, ah0, al0, ah1, al1);
    asm volatile("s_waitcnt vmcnt(0)" ::: "memory");
    __builtin_amdgcn_s_barrier();
  }
#undef S_MFMA_PAIR

  // ---- epilogue ----
#pragma unroll
  for (int i = 0; i < 8; ++i)
#pragma unroll
    for (int j = 0; j < 4; ++j) {
      int col = n0 + wc * 64 + j * 16 + l16;
      int rw = m0 + wr * 128 + i * 16 + quad * 4;
#pragma unroll
      for (int r2 = 0; r2 < 4; ++r2)
        S[(size_t)(rw + r2) * NROWS + col] = acc[i][j][r2];
    }
}

// ---------- softmax: row of S (fp32) -> PACKED bf16 P (plain layout) ----------
__global__ __launch_bounds__(256) void softmax_pack(const float* __restrict__ S,
                                                    ushort* __restrict__ P) {
  const int row = blockIdx.x, t = threadIdx.x;
  const float* Sr = S + (size_t)row * NROWS;
  const f32x4* S4 = (const f32x4*)Sr;
  f32x4 v[4];
  float mx = -3.4e38f;
#pragma unroll
  for (int c = 0; c < 4; ++c) {
    v[c] = S4[c * 256 + t];
    mx = fmaxf(mx, fmaxf(fmaxf(v[c].x, v[c].y), fmaxf(v[c].z, v[c].w)));
  }
  __shared__ float red[4];
  for (int o = 32; o >= 1; o >>= 1) mx = fmaxf(mx, __shfl_xor(mx, o));
  int wv = t >> 6, ln = t & 63;
  if (ln == 0) red[wv] = mx;
  __syncthreads();
  mx = fmaxf(fmaxf(red[0], red[1]), fmaxf(red[2], red[3]));
  float s = 0.f;
#pragma unroll
  for (int c = 0; c < 4; ++c) {
    v[c].x = __expf(v[c].x - mx);
    v[c].y = __expf(v[c].y - mx);
    v[c].z = __expf(v[c].z - mx);
    v[c].w = __expf(v[c].w - mx);
    s += v[c].x + v[c].y + v[c].z + v[c].w;
  }
  for (int o = 32; o >= 1; o >>= 1) s += __shfl_xor(s, o);
  __syncthreads();
  if (ln == 0) red[wv] = s;
  __syncthreads();
  s = red[0] + red[1] + red[2] + red[3];
  float inv = 1.f / s;
#pragma unroll
  for (int c = 0; c < 4; ++c) {
    ushort4 h;
    h.x = f2bf(v[c].x * inv);
    h.y = f2bf(v[c].y * inv);
    h.z = f2bf(v[c].z * inv);
    h.w = f2bf(v[c].w * inv);
    int c0 = 1024 * c + 4 * t;            // 4 consecutive cols, 8B-aligned in packed space
    *(ushort4*)(P + pidx(row, c0, NROWS / 32)) = h;
  }
}

// ---------- Out = P*V, LDS-free, barrier-free; BM=128 ----------
__global__ __launch_bounds__(256) void gemm_pv(const ushort* __restrict__ P,
                                               const ushort* __restrict__ Vt,
                                               float* __restrict__ Out) {
  const int n0 = blockIdx.x * 128, m0 = blockIdx.y * 128;
  const int t = threadIdx.x;
  const int wv = t >> 6, ln = t & 63;
  const int quad = ln >> 4, l16 = ln & 15;

  f32x4 acc[4][4];
#pragma unroll
  for (int i = 0; i < 4; ++i)
#pragma unroll
    for (int j = 0; j < 4; ++j) acc[i][j] = (f32x4){0.f, 0.f, 0.f, 0.f};

  direct_gemm<4, false, NROWS / 32, 512, 512>(P, Vt, m0, n0, acc);

#pragma unroll
  for (int i = 0; i < 4; ++i)
#pragma unroll
    for (int j = 0; j < 4; ++j) {
      int col = n0 + (wv & 1) * 64 + j * 16 + l16;
      int rw = m0 + (wv >> 1) * 64 + i * 16 + quad * 4;
#pragma unroll
      for (int r2 = 0; r2 < 4; ++r2)
        Out[(size_t)(rw + r2) * DDIM + col] = acc[i][j][r2];
    }
}

extern "C" void kernel_launch(void* const* d_in, const int* in_sizes, int n_in,
                              void* d_out, int out_size, void* d_ws, size_t ws_size,
                              hipStream_t stream) {
  const float* x  = (const float*)d_in[0];
  const float* wq = (const float*)d_in[1];
  const float* wk = (const float*)d_in[2];
  const float* wv = (const float*)d_in[3];
  char* ws = (char*)d_ws;
  const size_t MB = 1u << 20;

  // Workspace map (peak 104 MiB):
  ushort* Vt  = (ushort*)(ws + 0);        // 0-8    plain packed, alive through pv
  ushort* Qc  = (ushort*)(ws + 8 * MB);   // 8-24   interleaved split Q (dead after gemm_s)
  ushort* Kc  = (ushort*)(ws + 24 * MB);  // 24-40  interleaved split K (dead after gemm_s)
  ushort* Pp  = (ushort*)(ws + 8 * MB);   // 8-40   plain packed P (aliases dead Q/K)
  ushort* Xc  = (ushort*)(ws + 40 * MB);  // 40-56  interleaved split X (dead after qkv)
  ushort* Wqc = (ushort*)(ws + 56 * MB);  // 56-60  interleaved split W^T (dead after qkv)
  ushort* Wkc = (ushort*)(ws + 60 * MB);  // 60-64
  ushort* Wvh = (ushort*)(ws + 64 * MB);  // 64-66  plain W_v^T
  float*  S   = (float*)(ws + 40 * MB);   // 40-104 (overwrites dead X/W)
  float*  Out = (float*)d_out;

  prep<<<4096, 256, 0, stream>>>(x, wq, wk, wv, Xc, Wqc, Wkc, Wvh);
  gemm_qkv<<<dim3(24, 32), 256, 0, stream>>>(Xc, Wqc, Wkc, Wvh, Qc, Kc, Vt);
  gemm_s<<<dim3(16, 16), 512, 0, stream>>>(Qc, Kc, S);
  softmax_pack<<<NROWS, 256, 0, stream>>>(S, Pp);
  gemm_pv<<<dim3(8, 32), 256, 0, stream>>>(Pp, Vt, Out);
}

// Round 9
// 314.600 us; speedup vs baseline: 1.0434x; 1.0026x over previous
//
#include <hip/hip_runtime.h>
#include <math.h>

#define NROWS 4096
#define DDIM  1024

typedef __attribute__((ext_vector_type(8))) short short8;
typedef __attribute__((ext_vector_type(4))) float f32x4;

// ---------- bf16 helpers (manual RNE) ----------
__device__ __forceinline__ ushort f2bf(float v) {
  union { float f; uint32_t u; } c; c.f = v;
  uint32_t u = c.u;
  uint32_t lsb = (u >> 16) & 1u;
  u += 0x7fffu + lsb;
  return (ushort)(u >> 16);
}
__device__ __forceinline__ float bf2f(ushort h) {
  union { uint32_t u; float f; } c; c.u = ((uint32_t)h) << 16;
  return c.f;
}

// ---------- async global->LDS, 16B per lane ----------
__device__ __forceinline__ void gll16(const void* g, void* l) {
  __builtin_amdgcn_global_load_lds((const __attribute__((address_space(1))) void*)g,
                                   (__attribute__((address_space(3))) void*)l, 16, 0, 0);
}

// ---------- packed-fragment layouts ----------
// PLAIN: [R][C] bf16 as 16x32 tiles of 1KB (512 ushorts). tile T = (r>>4)*ldt+(c>>5);
//   intra ushort = ((c>>3)&3)*128 + (r&15)*8 + (c&7). Lane ln reads 16B at T*512+ln*8.
__device__ __forceinline__ size_t pidx(int r, int c, int ldt) {
  return ((size_t)((r >> 4) * ldt + (c >> 5))) * 512 +
         ((c >> 3) & 3) * 128 + (r & 15) * 8 + (c & 7);
}
// SPLIT-INTERLEAVED: hi fragment (512 ushorts) immediately followed by its lo
// fragment: tile T occupies 1024 ushorts; hi at T*1024+intra, lo at +512.
__device__ __forceinline__ size_t pidxs(int r, int c, int ldt) {
  return ((size_t)((r >> 4) * ldt + (c >> 5))) * 1024 +
         ((c >> 3) & 3) * 128 + (r & 15) * 8 + (c & 7);
}

// ---------- prep: split x + transpose/split 3 weights, packed outputs ----------
__global__ __launch_bounds__(256) void prep(const float* __restrict__ x,
                                            const float* __restrict__ wq,
                                            const float* __restrict__ wk,
                                            const float* __restrict__ wv,
                                            ushort* Xc,
                                            ushort* Wqc, ushort* Wkc, ushort* Wvh) {
  __shared__ float tl[32][33];
  const int b = blockIdx.x, t = threadIdx.x;
  if (b < 1024) {
    const f32x4* src = (const f32x4*)x;
#pragma unroll
    for (int r = 0; r < 4; ++r) {
      int i = b * 1024 + r * 256 + t;       // float4 index over [4096][256]
      int row = i >> 8;
      int c = (i & 255) << 2;               // 4-aligned column
      f32x4 v = __builtin_nontemporal_load(src + i);
      ushort4 h, l;
      h.x = f2bf(v.x); l.x = f2bf(v.x - bf2f(h.x));
      h.y = f2bf(v.y); l.y = f2bf(v.y - bf2f(h.y));
      h.z = f2bf(v.z); l.z = f2bf(v.z - bf2f(h.z));
      h.w = f2bf(v.w); l.w = f2bf(v.w - bf2f(h.w));
      size_t o = pidxs(row, c, DDIM / 32);  // (c&7)∈{0,4} -> 8B aligned
      *(ushort4*)(Xc + o) = h;
      *(ushort4*)(Xc + o + 512) = l;
    }
  } else {
    const int z = (b - 1024) >> 10;
    const int tile = (b - 1024) & 1023;
    const float* src = z == 0 ? wq : (z == 1 ? wk : wv);
    const int r0 = (tile >> 5) * 32;
    const int c0 = (tile & 31) * 32;
    const int tx = t & 31, ty = t >> 5;
    for (int i = ty; i < 32; i += 8)
      tl[i][tx] = __builtin_nontemporal_load(&src[(size_t)(r0 + i) * DDIM + c0 + tx]);
    __syncthreads();
    if (z == 2) {
      for (int i = ty; i < 32; i += 8) {
        float v = tl[tx][i];                // = W[r0+tx][c0+i]
        Wvh[pidx(c0 + i, r0 + tx, DDIM / 32)] = f2bf(v);
      }
    } else {
      ushort* d = z == 0 ? Wqc : Wkc;
      for (int i = ty; i < 32; i += 8) {
        float v = tl[tx][i];                // = W[r0+tx][c0+i]
        ushort h = f2bf(v);
        size_t o = pidxs(c0 + i, r0 + tx, DDIM / 32);  // W^T packed interleaved
        d[o] = h;
        d[o + 512] = f2bf(v - bf2f(h));
      }
    }
  }
}

// ---------- LDS-free, barrier-free direct packed-fragment GEMM core ----------
// (kept for gemm_qkv / gemm_pv)
template <int MI, bool SPLIT, int KT, int SA, int SB>
__device__ __forceinline__ void direct_gemm(const ushort* __restrict__ A,
                                            const ushort* __restrict__ B,
                                            int m0, int n0, f32x4 (*acc)[4]) {
  const int t = threadIdx.x;
  const int wv = t >> 6, ln = t & 63;
  const int arb = (wv >> 1) * (MI * 16), crb = (wv & 1) * 64;
  const int ra = (m0 + arb) >> 4;
  const int rb = (n0 + crb) >> 4;

  uint oA[MI], oB[4];
#pragma unroll
  for (int i = 0; i < MI; ++i) oA[i] = (uint)(ra + i) * (uint)(KT * SA) + (uint)ln * 8u;
#pragma unroll
  for (int j = 0; j < 4; ++j) oB[j] = (uint)(rb + j) * (uint)(KT * SB) + (uint)ln * 8u;

  short8 ah0[MI], al0[MI], bh0[4], bl0[4];
  short8 ah1[MI], al1[MI], bh1[4], bl1[4];

#define DG_LOAD(sidx, AH, AL, BH, BL)                                        \
  {                                                                          \
    uint sa_ = (uint)(sidx) * (uint)SA;                                      \
    uint sb_ = (uint)(sidx) * (uint)SB;                                      \
    _Pragma("unroll") for (int i_ = 0; i_ < MI; ++i_) {                      \
      const ushort* pa_ = A + oA[i_] + sa_;                                  \
      AH[i_] = *(const short8*)pa_;                                          \
      if constexpr (SPLIT) AL[i_] = *(const short8*)(pa_ + 512);             \
    }                                                                        \
    _Pragma("unroll") for (int j_ = 0; j_ < 4; ++j_) {                       \
      const ushort* pb_ = B + oB[j_] + sb_;                                  \
      BH[j_] = *(const short8*)pb_;                                          \
      if constexpr (SPLIT) BL[j_] = *(const short8*)(pb_ + 512);             \
    }                                                                        \
  }

#define DG_MFMA(AH, AL, BH, BL)                                              \
  {                                                                          \
    __builtin_amdgcn_s_setprio(1);                                           \
    _Pragma("unroll") for (int j_ = 0; j_ < 4; ++j_) {                       \
      _Pragma("unroll") for (int i_ = 0; i_ < MI; ++i_) {                    \
        acc[i_][j_] = __builtin_amdgcn_mfma_f32_16x16x32_bf16(               \
            AH[i_], BH[j_], acc[i_][j_], 0, 0, 0);                           \
        if constexpr (SPLIT) {                                               \
          acc[i_][j_] = __builtin_amdgcn_mfma_f32_16x16x32_bf16(             \
              AH[i_], BL[j_], acc[i_][j_], 0, 0, 0);                         \
          acc[i_][j_] = __builtin_amdgcn_mfma_f32_16x16x32_bf16(             \
              AL[i_], BH[j_], acc[i_][j_], 0, 0, 0);                         \
        }                                                                    \
      }                                                                      \
    }                                                                        \
    __builtin_amdgcn_s_setprio(0);                                           \
  }

  DG_LOAD(0, ah0, al0, bh0, bl0);
#pragma unroll 1
  for (int s = 0; s < KT - 2; s += 2) {
    DG_LOAD(s + 1, ah1, al1, bh1, bl1);
    DG_MFMA(ah0, al0, bh0, bl0);
    DG_LOAD(s + 2, ah0, al0, bh0, bl0);
    DG_MFMA(ah1, al1, bh1, bl1);
  }
  DG_LOAD(KT - 1, ah1, al1, bh1, bl1);
  DG_MFMA(ah0, al0, bh0, bl0);
  DG_MFMA(ah1, al1, bh1, bl1);

#undef DG_LOAD
#undef DG_MFMA
}

// ---------- fused QKV: direct-packed, no LDS, no barriers; XCD-chunked swizzle ----------
__global__ __launch_bounds__(256) void gemm_qkv(const ushort* __restrict__ Xc,
                                                const ushort* __restrict__ Wqc,
                                                const ushort* __restrict__ Wkc,
                                                const ushort* __restrict__ Wvh,
                                                ushort* Qc, ushort* Kc, ushort* Vt) {
  const int id = blockIdx.y * 24 + blockIdx.x;
  const int wg = (id & 7) * 96 + (id >> 3);
  const int bx = wg % 24, by = wg / 24;
  const int which = bx % 3;
  const int g = bx / 3;                      // 0..7 (d_out slice)
  const int t = threadIdx.x;
  const int wv = t >> 6, ln = t & 63;
  const int quad = ln >> 4, l16 = ln & 15;

  f32x4 acc[4][4];
#pragma unroll
  for (int i = 0; i < 4; ++i)
#pragma unroll
    for (int j = 0; j < 4; ++j) acc[i][j] = (f32x4){0.f, 0.f, 0.f, 0.f};

  if (which == 2) {
    const int m0 = g * 128;                  // d over 1024
    const int n0 = by * 128;                 // kv over 4096
    direct_gemm<4, false, DDIM / 32, 512, 1024>(Wvh, Xc, m0, n0, acc);
#pragma unroll
    for (int i = 0; i < 4; ++i)
#pragma unroll
      for (int j = 0; j < 4; ++j) {
        int kv = n0 + (wv & 1) * 64 + j * 16 + l16;
        int d = m0 + (wv >> 1) * 64 + i * 16 + quad * 4;
#pragma unroll
        for (int r2 = 0; r2 < 4; ++r2)
          Vt[pidx(d + r2, kv, NROWS / 32)] = f2bf(acc[i][j][r2]);
      }
  } else {
    const int n0 = g * 128;                  // d over 1024
    const int m0 = by * 128;                 // rows over 4096
    const ushort* Bc = which ? Wkc : Wqc;
    direct_gemm<4, true, DDIM / 32, 1024, 1024>(Xc, Bc, m0, n0, acc);
    const float scale = which ? 1.0f : 0.03125f;  // fold 1/sqrt(1024) into Q
    ushort* D = which ? Kc : Qc;
#pragma unroll
    for (int i = 0; i < 4; ++i)
#pragma unroll
      for (int j = 0; j < 4; ++j) {
        int col = n0 + (wv & 1) * 64 + j * 16 + l16;
        int rw = m0 + (wv >> 1) * 64 + i * 16 + quad * 4;
#pragma unroll
        for (int r2 = 0; r2 < 4; ++r2) {
          float v = acc[i][j][r2] * scale;
          ushort h = f2bf(v);
          size_t o = pidxs(rw + r2, col, DDIM / 32);
          D[o] = h;
          D[o + 512] = f2bf(v - bf2f(h));
        }
      }
  }
}

// ---------- S = Q*K^T (split): 256x256 tile, 8 waves, single-barrier LDS schedule ----
// Double-buffered 128KB LDS; packed fragments -> linear gll16 staging and
// conflict-free contiguous ds_read_b128. Per kt: stage tile kt+1 into buf nb
// (issued FIRST so loads stay in flight under the MFMAs), read B + 4 A-pairs
// from buf cb with compiler-scheduled counted lgkmcnt, run 96 MFMAs, then
// vmcnt(0) + ONE barrier. Correctness: reads target cb only, staging targets
// nb only; the end barrier orders (a) nb staging visible before kt+1 reads,
// (b) cb reads complete before kt+1 re-stages cb.
__global__ __launch_bounds__(512) void gemm_s(const ushort* __restrict__ Qc,
                                              const ushort* __restrict__ Kc,
                                              float* __restrict__ S) {
  __shared__ char smem[2][65536];
  const int bid = blockIdx.y * 16 + blockIdx.x;
  const int xcd = bid & 7, local = bid >> 3;   // 256 blocks = 1/CU
  // XCD region: 4 tile-rows x 8 tile-cols (bijective)
  const int m0 = ((xcd >> 1) * 4 + (local & 3)) * 256;
  const int n0 = ((xcd & 1) * 8 + (local >> 2)) * 256;
  const int t = threadIdx.x;
  const int w = t >> 6, ln = t & 63;
  const int wr = w >> 2, wc = w & 3;           // 2(M) x 4(N) wave grid
  const int quad = ln >> 4, l16 = ln & 15;

  // ---- staging source: each wave stages 4 frag-pairs (8KB) per tile ----
  // frag-row stride = 32 tiles * 2048B = 65536B
  const char* srcBase = (w < 4)
      ? (const char*)Qc + (size_t)((m0 >> 4) + w * 4) * 65536
      : (const char*)Kc + (size_t)((n0 >> 4) + (w - 4) * 4) * 65536;
  srcBase += ln * 16;
  char* ldsBase = (char*)smem + w * 8192 + ln * 16;  // + buf*65536 + u*1024

  f32x4 acc[8][4];
#pragma unroll
  for (int i = 0; i < 8; ++i)
#pragma unroll
    for (int j = 0; j < 4; ++j) acc[i][j] = (f32x4){0.f, 0.f, 0.f, 0.f};

  // ---- prologue: stage tile 0 into buf 0 ----
#pragma unroll
  for (int u = 0; u < 8; ++u)
    gll16(srcBase + (u >> 1) * 65536 + (u & 1) * 1024, ldsBase + u * 1024);
  asm volatile("s_waitcnt vmcnt(0)" ::: "memory");
  __builtin_amdgcn_s_barrier();

  const char* aB = (char*)smem + (wr * 8) * 2048 + ln * 16;
  const char* bB = (char*)smem + 32768 + (wc * 4) * 2048 + ln * 16;

#pragma unroll 1
  for (int kt = 0; kt < 32; ++kt) {
    const int cb = (kt & 1) << 16;             // current buffer byte offset
    const int nb = ((kt + 1) & 1) << 16;       // next buffer byte offset
    const char* srcK = srcBase + (size_t)(kt + 1) * 2048;

    // issue next-tile staging FIRST: in flight under this kt's compute
    if (kt < 31) {
#pragma unroll
      for (int u = 0; u < 8; ++u)
        gll16(srcK + (u >> 1) * 65536 + (u & 1) * 1024, ldsBase + nb + u * 1024);
    }

    short8 bh[4], bl[4];
#pragma unroll
    for (int j = 0; j < 4; ++j) {
      bh[j] = *(const short8*)(bB + cb + j * 2048);
      bl[j] = *(const short8*)(bB + cb + j * 2048 + 1024);
    }

#pragma unroll
    for (int p = 0; p < 4; ++p) {
      short8 ah0 = *(const short8*)(aB + cb + (2 * p) * 2048);
      short8 al0 = *(const short8*)(aB + cb + (2 * p) * 2048 + 1024);
      short8 ah1 = *(const short8*)(aB + cb + (2 * p + 1) * 2048);
      short8 al1 = *(const short8*)(aB + cb + (2 * p + 1) * 2048 + 1024);
      __builtin_amdgcn_s_setprio(1);
#pragma unroll
      for (int j_ = 0; j_ < 4; ++j_) {
        acc[2 * p][j_] = __builtin_amdgcn_mfma_f32_16x16x32_bf16(ah0, bh[j_], acc[2 * p][j_], 0, 0, 0);
        acc[2 * p][j_] = __builtin_amdgcn_mfma_f32_16x16x32_bf16(ah0, bl[j_], acc[2 * p][j_], 0, 0, 0);
        acc[2 * p][j_] = __builtin_amdgcn_mfma_f32_16x16x32_bf16(al0, bh[j_], acc[2 * p][j_], 0, 0, 0);
        acc[2 * p + 1][j_] = __builtin_amdgcn_mfma_f32_16x16x32_bf16(ah1, bh[j_], acc[2 * p + 1][j_], 0, 0, 0);
        acc[2 * p + 1][j_] = __builtin_amdgcn_mfma_f32_16x16x32_bf16(ah1, bl[j_], acc[2 * p + 1][j_], 0, 0, 0);
        acc[2 * p + 1][j_] = __builtin_amdgcn_mfma_f32_16x16x32_bf16(al1, bh[j_], acc[2 * p + 1][j_], 0, 0, 0);
      }
      __builtin_amdgcn_s_setprio(0);
    }

    asm volatile("s_waitcnt vmcnt(0)" ::: "memory");
    __builtin_amdgcn_s_barrier();
  }

  // ---- epilogue ----
#pragma unroll
  for (int i = 0; i < 8; ++i)
#pragma unroll
    for (int j = 0; j < 4; ++j) {
      int col = n0 + wc * 64 + j * 16 + l16;
      int rw = m0 + wr * 128 + i * 16 + quad * 4;
#pragma unroll
      for (int r2 = 0; r2 < 4; ++r2)
        S[(size_t)(rw + r2) * NROWS + col] = acc[i][j][r2];
    }
}

// ---------- softmax: row of S (fp32) -> PACKED bf16 P (plain layout) ----------
__global__ __launch_bounds__(256) void softmax_pack(const float* __restrict__ S,
                                                    ushort* __restrict__ P) {
  const int row = blockIdx.x, t = threadIdx.x;
  const float* Sr = S + (size_t)row * NROWS;
  const f32x4* S4 = (const f32x4*)Sr;
  f32x4 v[4];
  float mx = -3.4e38f;
#pragma unroll
  for (int c = 0; c < 4; ++c) {
    v[c] = S4[c * 256 + t];
    mx = fmaxf(mx, fmaxf(fmaxf(v[c].x, v[c].y), fmaxf(v[c].z, v[c].w)));
  }
  __shared__ float red[4];
  for (int o = 32; o >= 1; o >>= 1) mx = fmaxf(mx, __shfl_xor(mx, o));
  int wv = t >> 6, ln = t & 63;
  if (ln == 0) red[wv] = mx;
  __syncthreads();
  mx = fmaxf(fmaxf(red[0], red[1]), fmaxf(red[2], red[3]));
  float s = 0.f;
#pragma unroll
  for (int c = 0; c < 4; ++c) {
    v[c].x = __expf(v[c].x - mx);
    v[c].y = __expf(v[c].y - mx);
    v[c].z = __expf(v[c].z - mx);
    v[c].w = __expf(v[c].w - mx);
    s += v[c].x + v[c].y + v[c].z + v[c].w;
  }
  for (int o = 32; o >= 1; o >>= 1) s += __shfl_xor(s, o);
  __syncthreads();
  if (ln == 0) red[wv] = s;
  __syncthreads();
  s = red[0] + red[1] + red[2] + red[3];
  float inv = 1.f / s;
#pragma unroll
  for (int c = 0; c < 4; ++c) {
    ushort4 h;
    h.x = f2bf(v[c].x * inv);
    h.y = f2bf(v[c].y * inv);
    h.z = f2bf(v[c].z * inv);
    h.w = f2bf(v[c].w * inv);
    int c0 = 1024 * c + 4 * t;            // 4 consecutive cols, 8B-aligned in packed space
    *(ushort4*)(P + pidx(row, c0, NROWS / 32)) = h;
  }
}

// ---------- Out = P*V, LDS-free, barrier-free; BM=128 ----------
__global__ __launch_bounds__(256) void gemm_pv(const ushort* __restrict__ P,
                                               const ushort* __restrict__ Vt,
                                               float* __restrict__ Out) {
  const int n0 = blockIdx.x * 128, m0 = blockIdx.y * 128;
  const int t = threadIdx.x;
  const int wv = t >> 6, ln = t & 63;
  const int quad = ln >> 4, l16 = ln & 15;

  f32x4 acc[4][4];
#pragma unroll
  for (int i = 0; i < 4; ++i)
#pragma unroll
    for (int j = 0; j < 4; ++j) acc[i][j] = (f32x4){0.f, 0.f, 0.f, 0.f};

  direct_gemm<4, false, NROWS / 32, 512, 512>(P, Vt, m0, n0, acc);

#pragma unroll
  for (int i = 0; i < 4; ++i)
#pragma unroll
    for (int j = 0; j < 4; ++j) {
      int col = n0 + (wv & 1) * 64 + j * 16 + l16;
      int rw = m0 + (wv >> 1) * 64 + i * 16 + quad * 4;
#pragma unroll
      for (int r2 = 0; r2 < 4; ++r2)
        Out[(size_t)(rw + r2) * DDIM + col] = acc[i][j][r2];
    }
}

extern "C" void kernel_launch(void* const* d_in, const int* in_sizes, int n_in,
                              void* d_out, int out_size, void* d_ws, size_t ws_size,
                              hipStream_t stream) {
  const float* x  = (const float*)d_in[0];
  const float* wq = (const float*)d_in[1];
  const float* wk = (const float*)d_in[2];
  const float* wv = (const float*)d_in[3];
  char* ws = (char*)d_ws;
  const size_t MB = 1u << 20;

  // Workspace map (peak 104 MiB):
  ushort* Vt  = (ushort*)(ws + 0);        // 0-8    plain packed, alive through pv
  ushort* Qc  = (ushort*)(ws + 8 * MB);   // 8-24   interleaved split Q (dead after gemm_s)
  ushort* Kc  = (ushort*)(ws + 24 * MB);  // 24-40  interleaved split K (dead after gemm_s)
  ushort* Pp  = (ushort*)(ws + 8 * MB);   // 8-40   plain packed P (aliases dead Q/K)
  ushort* Xc  = (ushort*)(ws + 40 * MB);  // 40-56  interleaved split X (dead after qkv)
  ushort* Wqc = (ushort*)(ws + 56 * MB);  // 56-60  interleaved split W^T (dead after qkv)
  ushort* Wkc = (ushort*)(ws + 60 * MB);  // 60-64
  ushort* Wvh = (ushort*)(ws + 64 * MB);  // 64-66  plain W_v^T
  float*  S   = (float*)(ws + 40 * MB);   // 40-104 (overwrites dead X/W)
  float*  Out = (float*)d_out;

  prep<<<4096, 256, 0, stream>>>(x, wq, wk, wv, Xc, Wqc, Wkc, Wvh);
  gemm_qkv<<<dim3(24, 32), 256, 0, stream>>>(Xc, Wqc, Wkc, Wvh, Qc, Kc, Vt);
  gemm_s<<<dim3(16, 16), 512, 0, stream>>>(Qc, Kc, S);
  softmax_pack<<<NROWS, 256, 0, stream>>>(S, Pp);
  gemm_pv<<<dim3(8, 32), 256, 0, stream>>>(Pp, Vt, Out);
}